// Round 7
// baseline (366.551 us; speedup 1.0000x reference)
//
#include <hip/hip_runtime.h>

#define DIN 256
#define NTOK 4096

typedef __bf16 bf16;
typedef __bf16 bf16x4 __attribute__((ext_vector_type(4)));
typedef __bf16 bf16x8 __attribute__((ext_vector_type(8)));
typedef float floatx16 __attribute__((ext_vector_type(16)));

__device__ inline floatx16 mfma32(bf16x8 a, bf16x8 b, floatx16 c) {
    return __builtin_amdgcn_mfma_f32_32x32x16_bf16(a, b, c, 0, 0, 0);
}

// async global->LDS, 16B per lane. g: per-lane global addr; l: wave-uniform LDS base.
__device__ inline void async16(const void* g, void* l) {
    __builtin_amdgcn_global_load_lds(
        (const __attribute__((address_space(1))) unsigned int*)g,
        (__attribute__((address_space(3))) unsigned int*)l, 16, 0, 0);
}

// pack two f32 -> u32 of 2 bf16 (lo = a)
__device__ inline unsigned pkbf(float a, float b) {
    union { bf16 e[2]; unsigned u; } x;
    x.e[0] = (bf16)a; x.e[1] = (bf16)b;
    return x.u;
}

// assemble B-frag: h==0 -> {a0,a1,a2,a3}, h==1 -> {b0,b1,b2,b3}
__device__ inline bf16x8 mkfrag(int h, unsigned a0, unsigned a1, unsigned a2, unsigned a3,
                                unsigned b0, unsigned b1, unsigned b2, unsigned b3) {
    union { unsigned u[4]; bf16x8 v; } x;
    x.u[0] = h ? b0 : a0; x.u[1] = h ? b1 : a1;
    x.u[2] = h ? b2 : a2; x.u[3] = h ? b3 : a3;
    return x.v;
}

// ---------------- kernel 1: cast weights to bf16 ----------------
__global__ void convert_w(const float* __restrict__ wq, const float* __restrict__ wk,
                          const float* __restrict__ wv, bf16* __restrict__ Wb) {
    int i = blockIdx.x * 256 + threadIdx.x;   // 0..196607
    const float* src = (i < 65536) ? wq : (i < 131072 ? wk : wv);
    Wb[i] = (bf16)src[i & 65535];
}

// ---------------- kernel 2: QKV projection v3b (unchanged) ----------------
__global__ __launch_bounds__(512, 2) void proj_kernel(
    const float* __restrict__ x, const bf16* __restrict__ Wb,
    bf16* __restrict__ Qo, bf16* __restrict__ Ko, bf16* __restrict__ Vo)
{
    __shared__ __attribute__((aligned(16))) char smem[131072];
    bf16 (*xs)[264] = (bf16(*)[264])smem;
    bf16* bufA = (bf16*)smem;
    bf16* bufB = (bf16*)(smem + 65536);

    int bid = blockIdx.x;
    int b = bid & 7, nt = bid >> 3;
    int n0 = nt * 128;
    int t = threadIdx.x;
    int lane = t & 63, w = t >> 6;
    int l32 = lane & 31, h = lane >> 5;
    int tokg = w >> 1;
    int og   = w & 1;

    int wofs[8];
#pragma unroll
    for (int jj = 0; jj < 8; ++jj) {
        int q = w * 8 + jj;
        int r2 = 2 * q + h;
        int cs = l32 ^ (r2 & 31);
        wofs[jj] = r2 * 512 + cs * 16;
    }

    {
        const float* xb = x + (size_t)b * DIN * NTOK;
#pragma unroll
        for (int it = 0; it < 16; ++it) {
            int flat = it * 512 + t;
            int c = flat >> 5;
            int nf = flat & 31;
            float4 v = *(const float4*)(xb + (size_t)c * NTOK + n0 + nf * 4);
            int nn = nf * 4;
            xs[nn + 0][c] = (bf16)v.x;
            xs[nn + 1][c] = (bf16)v.y;
            xs[nn + 2][c] = (bf16)v.z;
            xs[nn + 3][c] = (bf16)v.w;
        }
    }
    __syncthreads();

    bf16x8 xf[16];
#pragma unroll
    for (int ks = 0; ks < 16; ++ks)
        xf[ks] = *(const bf16x8*)&xs[tokg * 32 + l32][ks * 16 + h * 8];

    __syncthreads();

    {
        const char* src = (const char*)Wb;
#pragma unroll
        for (int jj = 0; jj < 8; ++jj)
            async16(src + wofs[jj], (char*)bufA + (w * 8 + jj) * 1024);
    }
    __syncthreads();

    for (int p = 0; p < 6; ++p) {
        if (p < 5) {
            bf16* nb = ((p + 1) & 1) ? bufB : bufA;
            const char* src = (const char*)Wb + (size_t)(p + 1) * 65536;
#pragma unroll
            for (int jj = 0; jj < 8; ++jj)
                async16(src + wofs[jj], (char*)nb + (w * 8 + jj) * 1024);
        }

        const bf16* wb = (p & 1) ? bufB : bufA;
        int mat = p >> 1, dhalf = p & 1;

        floatx16 acc[2];
#pragma unroll
        for (int dc = 0; dc < 2; ++dc)
#pragma unroll
            for (int i = 0; i < 16; ++i) acc[dc][i] = 0.0f;

        if (mat < 2) {
#pragma unroll
            for (int ks = 0; ks < 16; ++ks) {
#pragma unroll
                for (int dc = 0; dc < 2; ++dc) {
                    int row = og * 64 + dc * 32 + l32;
                    bf16x8 wf = *(const bf16x8*)((const char*)wb + row * 512 +
                                                 (((2 * ks + h) ^ (row & 31)) * 16));
                    acc[dc] = mfma32(xf[ks], wf, acc[dc]);
                }
            }
            bf16* Out = (mat == 0 ? Qo : Ko) + (size_t)b * NTOK * DIN;
#pragma unroll
            for (int dc = 0; dc < 2; ++dc) {
                int d = dhalf * 128 + og * 64 + dc * 32 + l32;
#pragma unroll
                for (int r = 0; r < 16; ++r) {
                    int tok = n0 + tokg * 32 + (r & 3) + 8 * (r >> 2) + 4 * h;
                    Out[(size_t)tok * DIN + d] = (bf16)acc[dc][r];
                }
            }
        } else {
#pragma unroll
            for (int ks = 0; ks < 16; ++ks) {
#pragma unroll
                for (int dc = 0; dc < 2; ++dc) {
                    int row = og * 64 + dc * 32 + l32;
                    bf16x8 wf = *(const bf16x8*)((const char*)wb + row * 512 +
                                                 (((2 * ks + h) ^ (row & 31)) * 16));
                    acc[dc] = mfma32(wf, xf[ks], acc[dc]);
                }
            }
            bf16* Out = Vo + (size_t)b * DIN * NTOK;
            int tok = n0 + tokg * 32 + l32;
#pragma unroll
            for (int dc = 0; dc < 2; ++dc)
#pragma unroll
                for (int r = 0; r < 16; ++r) {
                    int d = dhalf * 128 + og * 64 + dc * 32 + (r & 3) + 8 * (r >> 2) + 4 * h;
                    Out[(size_t)d * NTOK + tok] = (bf16)acc[dc][r];
                }
        }
        __syncthreads();
    }
}

// ---------------- kernel 3: attention v6 — homogeneous waves, P in registers ----------------
// R6 diagnosis: MfmaUtil pinned at 37% = 64 MFMA/SIMD/iter x 32.3cyc / 5600 wall across
// ALL variants (traffic/drain/occupancy all refuted). Cause: producer/consumer split
// phase-locks waves via the per-iter barrier + P's LDS round-trip -> MFMA pipe idles
// in every non-MFMA phase. v6: each wave owns 32q x 256d and does S -> exp -> PV itself;
// P^T never leaves registers (st's C-layout col=q=l32 IS PV's B-operand lane layout;
// only fix-up is the h-half kv exchange: 16 pkbf + 16 shfl_xor(32) per tile = T12).
// K in LDS (2-buf, R2 staging); V from global, L1-broadcast across waves (R3-proven).
// 128 thr x 512 blocks -> 2 independent blocks/CU (de-phased barriers), batch-pinned
// XCD (b=bid&7). launch_bounds(128,1): VGPR cap 512 -> spill-impossible; 1 wave/SIMD
// by design, latency hidden by ILP (8 indep PV chains, 2 S chains).
// Pre-committed failure test: attn >=140us with MfmaUtil <=42 -> theory wrong, plateau.

#define TILE_COMPUTE(TILE, KS)                                                    \
    {                                                                             \
        const bf16* Krd = (const bf16*)(KS) + l32 * 256;                          \
        floatx16 st0, st1;                                                        \
        _Pragma("unroll")                                                         \
        for (int i = 0; i < 16; ++i) { st0[i] = 0.0f; st1[i] = 0.0f; }            \
        _Pragma("unroll")                                                         \
        for (int ks = 0; ks < 16; ++ks) {                                         \
            int co = ((2 * ks + h) ^ lkey) * 8;                                   \
            bf16x8 kf0 = *(const bf16x8*)(Krd + co);                              \
            bf16x8 kf1 = *(const bf16x8*)(Krd + 32 * 256 + co);                   \
            st0 = mfma32(kf0, qf[ks], st0);                                       \
            st1 = mfma32(kf1, qf[ks], st1);                                       \
        }                                                                         \
        _Pragma("unroll")                                                         \
        for (int i = 0; i < 16; ++i) {                                            \
            float e0 = __expf(st0[i] * 0.0625f); lsum += e0; st0[i] = e0;         \
            float e1 = __expf(st1[i] * 0.0625f); lsum += e1; st1[i] = e1;         \
        }                                                                         \
        unsigned pA0 = pkbf(st0[0], st0[1]),   pB0 = pkbf(st0[2], st0[3]);        \
        unsigned pC0 = pkbf(st0[4], st0[5]),   pD0 = pkbf(st0[6], st0[7]);        \
        unsigned pE0 = pkbf(st0[8], st0[9]),   pF0 = pkbf(st0[10], st0[11]);      \
        unsigned pG0 = pkbf(st0[12], st0[13]), pH0 = pkbf(st0[14], st0[15]);      \
        unsigned pA1 = pkbf(st1[0], st1[1]),   pB1 = pkbf(st1[2], st1[3]);        \
        unsigned pC1 = pkbf(st1[4], st1[5]),   pD1 = pkbf(st1[6], st1[7]);        \
        unsigned pE1 = pkbf(st1[8], st1[9]),   pF1 = pkbf(st1[10], st1[11]);      \
        unsigned pG1 = pkbf(st1[12], st1[13]), pH1 = pkbf(st1[14], st1[15]);      \
        unsigned sA0 = __shfl_xor(pA0, 32), sB0 = __shfl_xor(pB0, 32);            \
        unsigned sC0 = __shfl_xor(pC0, 32), sD0 = __shfl_xor(pD0, 32);            \
        unsigned sE0 = __shfl_xor(pE0, 32), sF0 = __shfl_xor(pF0, 32);            \
        unsigned sG0 = __shfl_xor(pG0, 32), sH0 = __shfl_xor(pH0, 32);            \
        unsigned sA1 = __shfl_xor(pA1, 32), sB1 = __shfl_xor(pB1, 32);            \
        unsigned sC1 = __shfl_xor(pC1, 32), sD1 = __shfl_xor(pD1, 32);            \
        unsigned sE1 = __shfl_xor(pE1, 32), sF1 = __shfl_xor(pF1, 32);            \
        unsigned sG1 = __shfl_xor(pG1, 32), sH1 = __shfl_xor(pH1, 32);            \
        bf16x8 pb0 = mkfrag(h, pA0, pB0, sA0, sB0, sC0, sD0, pC0, pD0);           \
        bf16x8 pb1 = mkfrag(h, pE0, pF0, sE0, sF0, sG0, sH0, pG0, pH0);           \
        bf16x8 pb2 = mkfrag(h, pA1, pB1, sA1, sB1, sC1, sD1, pC1, pD1);           \
        bf16x8 pb3 = mkfrag(h, pE1, pF1, sE1, sF1, sG1, sH1, pG1, pH1);           \
        const bf16* Vt = Vb + (TILE) * 64 + h * 8;                                \
        _Pragma("unroll")                                                         \
        for (int db = 0; db < 8; ++db) {                                          \
            const bf16* vrow = Vt + (size_t)(db * 32 + l32) * NTOK;               \
            bf16x8 va0 = *(const bf16x8*)(vrow);                                  \
            bf16x8 va1 = *(const bf16x8*)(vrow + 16);                             \
            bf16x8 va2 = *(const bf16x8*)(vrow + 32);                             \
            bf16x8 va3 = *(const bf16x8*)(vrow + 48);                             \
            oacc[db] = mfma32(va0, pb0, oacc[db]);                                \
            oacc[db] = mfma32(va1, pb1, oacc[db]);                                \
            oacc[db] = mfma32(va2, pb2, oacc[db]);                                \
            oacc[db] = mfma32(va3, pb3, oacc[db]);                                \
        }                                                                         \
    }

__global__ __launch_bounds__(128, 1) void attn_kernel(
    const bf16* __restrict__ Q, const bf16* __restrict__ K,
    const bf16* __restrict__ V, float* __restrict__ out)
{
    __shared__ bf16 Ks[2][64][256];   // 64 KB -> 2 blocks/CU

    int bid = blockIdx.x;
    int b = bid & 7, qt = bid >> 3;   // batch -> XCD pinned; 64 q-tiles per batch
    int n0 = qt * 64;
    int t = threadIdx.x, lane = t & 63, w = t >> 6;   // 2 waves
    int l32 = lane & 31, h = lane >> 5;
    int lkey = (l32 & 7) ^ ((l32 >> 3) & 3);

    const bf16* Qb = Q + (size_t)b * NTOK * DIN;
    const bf16* Kb = K + (size_t)b * NTOK * DIN;
    const bf16* Vb = V + (size_t)b * DIN * NTOK;

    // K staging: 2 waves x 16 chunk-groups cover 64 rows x 256 (32KB)
    int koff[16];
#pragma unroll
    for (int jj = 0; jj < 16; ++jj) {
        int q = w * 16 + jj;
        int r = 2 * q + h;
        int ck = l32 ^ ((r & 7) ^ ((r >> 3) & 3));
        koff[jj] = (r * 256 + ck * 8) * 2;
    }

    // Q fragments: wave owns q-rows n0 + w*32 .. +31
    bf16x8 qf[16];
    {
        const bf16* qrow = Qb + (size_t)(n0 + w * 32 + l32) * DIN + h * 8;
#pragma unroll
        for (int ks = 0; ks < 16; ++ks) qf[ks] = *(const bf16x8*)(qrow + ks * 16);
    }

    floatx16 oacc[8];
#pragma unroll
    for (int i = 0; i < 8; ++i)
#pragma unroll
        for (int j = 0; j < 16; ++j) oacc[i][j] = 0.0f;
    float lsum = 0.0f;

    // prologue: K0->Ks[0], K1->Ks[1]
#pragma unroll
    for (int jj = 0; jj < 16; ++jj) {
        async16((const char*)Kb + koff[jj], (bf16*)Ks[0] + (w * 16 + jj) * 512);
        async16((const char*)Kb + 32768 + koff[jj], (bf16*)Ks[1] + (w * 16 + jj) * 512);
    }
    __syncthreads();

    TILE_COMPUTE(0, Ks[0]);
    __syncthreads();

    // iter mt: DMA K(mt+2) -> Ks[mt&1] (read finished last iter); compute tile mt+1
#pragma unroll 1
    for (int mt = 0; mt < 63; ++mt) {
        if (mt < 62) {
            int kadd = (mt + 2) * 32768;
#pragma unroll
            for (int jj = 0; jj < 16; ++jj)
                async16((const char*)Kb + kadd + koff[jj],
                        (bf16*)Ks[mt & 1] + (w * 16 + jj) * 512);
        }
        TILE_COMPUTE(mt + 1, Ks[(mt + 1) & 1]);
        __syncthreads();
    }

    // epilogue: denominator = own half + partner half; direct global writes
    float tot = lsum + __shfl_xor(lsum, 32);
    float rinv = 1.0f / tot;
    float* ob = out + (size_t)b * DIN * NTOK;
    int tok = n0 + w * 32 + l32;
#pragma unroll
    for (int db = 0; db < 8; ++db)
#pragma unroll
        for (int r = 0; r < 16; ++r) {
            int d = db * 32 + (r & 3) + 8 * (r >> 2) + 4 * h;
            ob[(size_t)d * NTOK + tok] = oacc[db][r] * rinv;
        }
}

// ---------------- launcher ----------------
extern "C" void kernel_launch(void* const* d_in, const int* in_sizes, int n_in,
                              void* d_out, int out_size, void* d_ws, size_t ws_size,
                              hipStream_t stream) {
    const float* x  = (const float*)d_in[0];
    const float* wq = (const float*)d_in[1];
    const float* wk = (const float*)d_in[2];
    const float* wv = (const float*)d_in[3];
    float* outf = (float*)d_out;

    char* ws = (char*)d_ws;
    bf16* Wb = (bf16*)(ws);                                  // 384 KB
    bf16* Qp = (bf16*)(ws + (1u << 20));                     // 16 MB
    bf16* Kp = (bf16*)(ws + (1u << 20) + (16u << 20));       // 16 MB
    bf16* Vp = (bf16*)(ws + (1u << 20) + (32u << 20));       // 16 MB

    convert_w<<<768, 256, 0, stream>>>(wq, wk, wv, Wb);
    proj_kernel<<<256, 512, 0, stream>>>(x, Wb, Qp, Kp, Vp);
    attn_kernel<<<512, 128, 0, stream>>>(Qp, Kp, Vp, outf);
}

// Round 8
// 243.497 us; speedup vs baseline: 1.5054x; 1.5054x over previous
//
#include <hip/hip_runtime.h>

#define DIN 256
#define NTOK 4096

typedef __bf16 bf16;
typedef __bf16 bf16x4 __attribute__((ext_vector_type(4)));
typedef __bf16 bf16x8 __attribute__((ext_vector_type(8)));
typedef float floatx16 __attribute__((ext_vector_type(16)));

__device__ inline floatx16 mfma32(bf16x8 a, bf16x8 b, floatx16 c) {
    return __builtin_amdgcn_mfma_f32_32x32x16_bf16(a, b, c, 0, 0, 0);
}

// async global->LDS, 16B per lane. g: per-lane global addr; l: wave-uniform LDS base.
__device__ inline void async16(const void* g, void* l) {
    __builtin_amdgcn_global_load_lds(
        (const __attribute__((address_space(1))) unsigned int*)g,
        (__attribute__((address_space(3))) unsigned int*)l, 16, 0, 0);
}

// ---------------- kernel 1: cast weights to bf16 ----------------
__global__ void convert_w(const float* __restrict__ wq, const float* __restrict__ wk,
                          const float* __restrict__ wv, bf16* __restrict__ Wb) {
    int i = blockIdx.x * 256 + threadIdx.x;   // 0..196607
    const float* src = (i < 65536) ? wq : (i < 131072 ? wk : wv);
    Wb[i] = (bf16)src[i & 65535];
}

// ---------------- kernel 2: QKV projection v3b (R4-proven) ----------------
__global__ __launch_bounds__(512, 2) void proj_kernel(
    const float* __restrict__ x, const bf16* __restrict__ Wb,
    bf16* __restrict__ Qo, bf16* __restrict__ Ko, bf16* __restrict__ Vo)
{
    __shared__ __attribute__((aligned(16))) char smem[131072];
    bf16 (*xs)[264] = (bf16(*)[264])smem;
    bf16* bufA = (bf16*)smem;
    bf16* bufB = (bf16*)(smem + 65536);

    int bid = blockIdx.x;
    int b = bid & 7, nt = bid >> 3;
    int n0 = nt * 128;
    int t = threadIdx.x;
    int lane = t & 63, w = t >> 6;
    int l32 = lane & 31, h = lane >> 5;
    int tokg = w >> 1;
    int og   = w & 1;

    int wofs[8];
#pragma unroll
    for (int jj = 0; jj < 8; ++jj) {
        int q = w * 8 + jj;
        int r2 = 2 * q + h;
        int cs = l32 ^ (r2 & 31);
        wofs[jj] = r2 * 512 + cs * 16;
    }

    {
        const float* xb = x + (size_t)b * DIN * NTOK;
#pragma unroll
        for (int it = 0; it < 16; ++it) {
            int flat = it * 512 + t;
            int c = flat >> 5;
            int nf = flat & 31;
            float4 v = *(const float4*)(xb + (size_t)c * NTOK + n0 + nf * 4);
            int nn = nf * 4;
            xs[nn + 0][c] = (bf16)v.x;
            xs[nn + 1][c] = (bf16)v.y;
            xs[nn + 2][c] = (bf16)v.z;
            xs[nn + 3][c] = (bf16)v.w;
        }
    }
    __syncthreads();

    bf16x8 xf[16];
#pragma unroll
    for (int ks = 0; ks < 16; ++ks)
        xf[ks] = *(const bf16x8*)&xs[tokg * 32 + l32][ks * 16 + h * 8];

    __syncthreads();

    {
        const char* src = (const char*)Wb;
#pragma unroll
        for (int jj = 0; jj < 8; ++jj)
            async16(src + wofs[jj], (char*)bufA + (w * 8 + jj) * 1024);
    }
    __syncthreads();

    for (int p = 0; p < 6; ++p) {
        if (p < 5) {
            bf16* nb = ((p + 1) & 1) ? bufB : bufA;
            const char* src = (const char*)Wb + (size_t)(p + 1) * 65536;
#pragma unroll
            for (int jj = 0; jj < 8; ++jj)
                async16(src + wofs[jj], (char*)nb + (w * 8 + jj) * 1024);
        }

        const bf16* wb = (p & 1) ? bufB : bufA;
        int mat = p >> 1, dhalf = p & 1;

        floatx16 acc[2];
#pragma unroll
        for (int dc = 0; dc < 2; ++dc)
#pragma unroll
            for (int i = 0; i < 16; ++i) acc[dc][i] = 0.0f;

        if (mat < 2) {
#pragma unroll
            for (int ks = 0; ks < 16; ++ks) {
#pragma unroll
                for (int dc = 0; dc < 2; ++dc) {
                    int row = og * 64 + dc * 32 + l32;
                    bf16x8 wf = *(const bf16x8*)((const char*)wb + row * 512 +
                                                 (((2 * ks + h) ^ (row & 31)) * 16));
                    acc[dc] = mfma32(xf[ks], wf, acc[dc]);
                }
            }
            bf16* Out = (mat == 0 ? Qo : Ko) + (size_t)b * NTOK * DIN;
#pragma unroll
            for (int dc = 0; dc < 2; ++dc) {
                int d = dhalf * 128 + og * 64 + dc * 32 + l32;
#pragma unroll
                for (int r = 0; r < 16; ++r) {
                    int tok = n0 + tokg * 32 + (r & 3) + 8 * (r >> 2) + 4 * h;
                    Out[(size_t)tok * DIN + d] = (bf16)acc[dc][r];
                }
            }
        } else {
#pragma unroll
            for (int ks = 0; ks < 16; ++ks) {
#pragma unroll
                for (int dc = 0; dc < 2; ++dc) {
                    int row = og * 64 + dc * 32 + l32;
                    bf16x8 wf = *(const bf16x8*)((const char*)wb + row * 512 +
                                                 (((2 * ks + h) ^ (row & 31)) * 16));
                    acc[dc] = mfma32(wf, xf[ks], acc[dc]);
                }
            }
            bf16* Out = Vo + (size_t)b * DIN * NTOK;
            int tok = n0 + tokg * 32 + l32;
#pragma unroll
            for (int dc = 0; dc < 2; ++dc)
#pragma unroll
                for (int r = 0; r < 16; ++r) {
                    int d = dhalf * 128 + og * 64 + dc * 32 + (r & 3) + 8 * (r >> 2) + 4 * h;
                    Out[(size_t)d * NTOK + tok] = (bf16)acc[dc][r];
                }
        }
        __syncthreads();
    }
}

// ---------------- kernel 3: attention (R2-proven structure + T5 setprio A/B) ----------------
// After 6 experiments (traffic R3, vmcnt R5, occupancy R1/R6, homogeneous R7) the
// producer/consumer 8-wave structure at 153.5us = 895 TF matches the documented
// plain-HIP attention plateau; every single-technique graft measured null/negative.
// This round: byte-exact R2 attn + setprio(1) around MFMA clusters only — the one
// single-variable T5 test never run unconfounded (R1 spill, R3 V-move confounds).
__global__ __launch_bounds__(512, 2) void attn_kernel(
    const bf16* __restrict__ Q, const bf16* __restrict__ K,
    const bf16* __restrict__ V, float* __restrict__ out)
{
    __shared__ bf16 Ks[2][64][256];   // 64 KB
    __shared__ bf16 Vs[2][256][64];   // 64 KB
    __shared__ bf16 Ps[2][128][64];   // 32 KB  (total 160 KB exactly)

    int bid = blockIdx.x;
    int b = bid & 7, qt = bid >> 3;   // batch -> XCD L2 locality
    int n0 = qt * 128;
    int t = threadIdx.x, lane = t & 63, w = t >> 6;
    int l32 = lane & 31, h = lane >> 5;
    int lkey = (l32 & 7) ^ ((l32 >> 3) & 3);   // swizzle key at every use site

    const bf16* Qb = Q + (size_t)b * NTOK * DIN;
    const bf16* Kb = K + (size_t)b * NTOK * DIN;
    const bf16* Vb = V + (size_t)b * DIN * NTOK;
    float* Lp = (float*)&Ps[0][0][0];   // reused AFTER last tile barrier (Ps dead)

    if (w < 4) {
        // ================= S-producer: S^T = K.Q^T =================
        int tokg = w >> 1, mg = w & 1;
        int krow = mg * 32 + l32;

        int koff[8];
#pragma unroll
        for (int jj = 0; jj < 8; ++jj) {
            int q = w * 8 + jj;
            int r = q * 2 + (lane >> 5);
            int ck = (lane & 31) ^ ((r & 7) ^ ((r >> 3) & 3));
            koff[jj] = (r * 256 + ck * 8) * 2;
        }

        bf16x8 qf[2][16];
#pragma unroll
        for (int ca = 0; ca < 2; ++ca) {
            const bf16* qrow = Qb + (size_t)(n0 + tokg * 64 + ca * 32 + l32) * DIN + h * 8;
#pragma unroll
            for (int ks = 0; ks < 16; ++ks) qf[ca][ks] = *(const bf16x8*)(qrow + ks * 16);
        }

        float lsum[2] = {0.0f, 0.0f};

        // prologue: K(0)->buf0, K(1)->buf1
#pragma unroll
        for (int jj = 0; jj < 8; ++jj) {
            async16((const char*)Kb + koff[jj], (bf16*)Ks[0] + (w * 8 + jj) * 512);
            async16((const char*)Kb + 32768 + koff[jj], (bf16*)Ks[1] + (w * 8 + jj) * 512);
        }
        __syncthreads();   // (1)

        // S^T(0) -> Ps[0]
        {
            const bf16* Krd = (const bf16*)Ks[0] + krow * 256;
            floatx16 st[2];
#pragma unroll
            for (int i = 0; i < 16; ++i) { st[0][i] = 0.0f; st[1][i] = 0.0f; }
            __builtin_amdgcn_s_setprio(1);
#pragma unroll
            for (int ks = 0; ks < 16; ++ks) {
                bf16x8 kf = *(const bf16x8*)(Krd + (((2 * ks + h) ^ lkey) * 8));
                st[0] = mfma32(kf, qf[0][ks], st[0]);
                st[1] = mfma32(kf, qf[1][ks], st[1]);
            }
            __builtin_amdgcn_s_setprio(0);
#pragma unroll
            for (int ca = 0; ca < 2; ++ca) {
                bf16* Prow = (bf16*)Ps[0] + (tokg * 64 + ca * 32 + l32) * 64;
                float tsum = 0.0f;
#pragma unroll
                for (int g = 0; g < 4; ++g) {
                    bf16x4 pk;
#pragma unroll
                    for (int i = 0; i < 4; ++i) {
                        float e = __expf(st[ca][g * 4 + i] * 0.0625f);
                        tsum += e;
                        pk[i] = (bf16)e;
                    }
                    *(bf16x4*)((char*)Prow + (((mg * 4 + g) ^ lkey) * 16) + h * 8) = pk;
                }
                lsum[ca] += tsum;
            }
        }
        __syncthreads();   // (2)

        for (int mt = 0; mt < 64; ++mt) {
            if (mt < 62) {   // DMA K(mt+2) -> Ks[mt&1]
                int kadd = (mt + 2) * 32768;
#pragma unroll
                for (int jj = 0; jj < 8; ++jj)
                    async16((const char*)Kb + kadd + koff[jj],
                            (bf16*)Ks[mt & 1] + (w * 8 + jj) * 512);
            }
            if (mt < 63) {
                const bf16* Krd = (const bf16*)Ks[(mt + 1) & 1] + krow * 256;
                floatx16 st[2];
#pragma unroll
                for (int i = 0; i < 16; ++i) { st[0][i] = 0.0f; st[1][i] = 0.0f; }
                __builtin_amdgcn_s_setprio(1);
#pragma unroll
                for (int ks = 0; ks < 16; ++ks) {
                    bf16x8 kf = *(const bf16x8*)(Krd + (((2 * ks + h) ^ lkey) * 8));
                    st[0] = mfma32(kf, qf[0][ks], st[0]);
                    st[1] = mfma32(kf, qf[1][ks], st[1]);
                }
                __builtin_amdgcn_s_setprio(0);
                bf16* Pw = (bf16*)Ps[(mt + 1) & 1];
#pragma unroll
                for (int ca = 0; ca < 2; ++ca) {
                    bf16* Prow = Pw + (tokg * 64 + ca * 32 + l32) * 64;
                    float tsum = 0.0f;
#pragma unroll
                    for (int g = 0; g < 4; ++g) {
                        bf16x4 pk;
#pragma unroll
                        for (int i = 0; i < 4; ++i) {
                            float e = __expf(st[ca][g * 4 + i] * 0.0625f);
                            tsum += e;
                            pk[i] = (bf16)e;
                        }
                        *(bf16x4*)((char*)Prow + (((mg * 4 + g) ^ lkey) * 16) + h * 8) = pk;
                    }
                    lsum[ca] += tsum;
                }
            }
            __syncthreads();   // single barrier per iter
        }

        // epilogue: h-pair reduce, publish row sums (Ps now dead -> Lp alias ok)
#pragma unroll
        for (int ca = 0; ca < 2; ++ca) {
            float sv = lsum[ca];
            sv += __shfl_xor(sv, 32);
            if (h == 0) Lp[mg * 128 + tokg * 64 + ca * 32 + l32] = sv;
        }
        __syncthreads();   // (3)
    } else {
        // ================= PV-consumer: O^T = V^T.P^T =================
        int slab = w - 4;

        int vofs[8];
#pragma unroll
        for (int jj = 0; jj < 8; ++jj) {
            int q = slab * 8 + jj;
            int d = q * 8 + (lane >> 3);
            int cv = (lane & 7) ^ ((d & 7) ^ ((d >> 3) & 3));
            vofs[jj] = (d * 4096 + cv * 8) * 2;
        }

        floatx16 oacc[8];   // [dc][tc]
#pragma unroll
        for (int i = 0; i < 8; ++i)
            for (int j = 0; j < 16; ++j) oacc[i][j] = 0.0f;

        // prologue: V(0)->buf0
#pragma unroll
        for (int jj = 0; jj < 8; ++jj)
            async16((const char*)Vb + vofs[jj], (bf16*)Vs[0] + (slab * 8 + jj) * 512);
        __syncthreads();   // (1)
        __syncthreads();   // (2)

        for (int mt = 0; mt < 64; ++mt) {
            if (mt < 63) {   // DMA V(mt+1) -> Vs[(mt+1)&1]
                int vadd = (mt + 1) * 128;
#pragma unroll
                for (int jj = 0; jj < 8; ++jj)
                    async16((const char*)Vb + vadd + vofs[jj],
                            (bf16*)Vs[(mt + 1) & 1] + (slab * 8 + jj) * 512);
            }
            const bf16* Vrd = (const bf16*)Vs[mt & 1];
            const char* Prd = (const char*)Ps[mt & 1];
#pragma unroll
            for (int kst = 0; kst < 4; ++kst) {
                bf16x8 va[2], pb[4];
#pragma unroll
                for (int dc = 0; dc < 2; ++dc) {
                    int d = slab * 64 + dc * 32 + l32;
                    va[dc] = *(const bf16x8*)(Vrd + d * 64 + (((kst * 2 + h) ^ lkey) * 8));
                }
#pragma unroll
                for (int tc = 0; tc < 4; ++tc)
                    pb[tc] = *(const bf16x8*)(Prd + (tc * 32 + l32) * 128 +
                                              (((kst * 2 + h) ^ lkey) * 16));
                __builtin_amdgcn_s_setprio(1);
#pragma unroll
                for (int dc = 0; dc < 2; ++dc)
#pragma unroll
                    for (int tc = 0; tc < 4; ++tc)
                        oacc[dc * 4 + tc] = mfma32(va[dc], pb[tc], oacc[dc * 4 + tc]);
                __builtin_amdgcn_s_setprio(0);
            }
            __syncthreads();   // single barrier per iter
        }

        __syncthreads();   // (3): Lp ready
        float* ob = out + (size_t)b * DIN * NTOK;
#pragma unroll
        for (int tc = 0; tc < 4; ++tc) {
            int tok = tc * 32 + l32;
            float rinv = 1.0f / (Lp[tok] + Lp[128 + tok]);
#pragma unroll
            for (int dc = 0; dc < 2; ++dc)
#pragma unroll
                for (int r = 0; r < 16; ++r) {
                    int d = slab * 64 + dc * 32 + (r & 3) + 8 * (r >> 2) + 4 * h;
                    ob[(size_t)d * NTOK + n0 + tok] = oacc[dc * 4 + tc][r] * rinv;
                }
        }
    }
}

// ---------------- launcher ----------------
extern "C" void kernel_launch(void* const* d_in, const int* in_sizes, int n_in,
                              void* d_out, int out_size, void* d_ws, size_t ws_size,
                              hipStream_t stream) {
    const float* x  = (const float*)d_in[0];
    const float* wq = (const float*)d_in[1];
    const float* wk = (const float*)d_in[2];
    const float* wv = (const float*)d_in[3];
    float* outf = (float*)d_out;

    char* ws = (char*)d_ws;
    bf16* Wb = (bf16*)(ws);                                  // 384 KB
    bf16* Qp = (bf16*)(ws + (1u << 20));                     // 16 MB
    bf16* Kp = (bf16*)(ws + (1u << 20) + (16u << 20));       // 16 MB
    bf16* Vp = (bf16*)(ws + (1u << 20) + (32u << 20));       // 16 MB

    convert_w<<<768, 256, 0, stream>>>(wq, wk, wv, Wb);
    proj_kernel<<<256, 512, 0, stream>>>(x, Wb, Qp, Kp, Vp);
    attn_kernel<<<256, 512, 0, stream>>>(Qp, Kp, Vp, outf);
}

// Round 9
// 241.469 us; speedup vs baseline: 1.5180x; 1.0084x over previous
//
#include <hip/hip_runtime.h>

#define DIN 256
#define NTOK 4096

typedef __bf16 bf16;
typedef __bf16 bf16x4 __attribute__((ext_vector_type(4)));
typedef __bf16 bf16x8 __attribute__((ext_vector_type(8)));
typedef float floatx16 __attribute__((ext_vector_type(16)));

__device__ inline floatx16 mfma32(bf16x8 a, bf16x8 b, floatx16 c) {
    return __builtin_amdgcn_mfma_f32_32x32x16_bf16(a, b, c, 0, 0, 0);
}

// async global->LDS, 16B per lane. g: per-lane global addr; l: wave-uniform LDS base.
__device__ inline void async16(const void* g, void* l) {
    __builtin_amdgcn_global_load_lds(
        (const __attribute__((address_space(1))) unsigned int*)g,
        (__attribute__((address_space(3))) unsigned int*)l, 16, 0, 0);
}

// ---------------- kernel 1: cast weights to bf16 (vectorized: float4 -> bf16x4) ----------------
__global__ void convert_w(const float* __restrict__ wq, const float* __restrict__ wk,
                          const float* __restrict__ wv, bf16* __restrict__ Wb) {
    int i = blockIdx.x * 256 + threadIdx.x;   // 0..49151 ; each handles 4 elements
    int i4 = i * 4;                            // 0..196604, 65536-aligned per matrix
    const float* src = (i4 < 65536) ? wq : (i4 < 131072 ? wk : wv);
    float4 v = *(const float4*)(src + (i4 & 65535));
    bf16x4 o;
    o[0] = (bf16)v.x; o[1] = (bf16)v.y; o[2] = (bf16)v.z; o[3] = (bf16)v.w;
    *(bf16x4*)(Wb + i4) = o;
}

// ---------------- kernel 2: QKV projection v3b (R4-proven) ----------------
// 128 tokens/block (grid 256, 8 waves), 128-row W tiles -> 6 phases, 32 MFMA/wave
// between barriers. W staged via global_load_lds 16B: linear LDS dest + pre-swizzled
// global source, reads apply same XOR (involution, key = row&31 on 16B chunks).
// x tile (67.6KB) aliased under the two 64KB W buffers (dead once xf is in regs).
__global__ __launch_bounds__(512, 2) void proj_kernel(
    const float* __restrict__ x, const bf16* __restrict__ Wb,
    bf16* __restrict__ Qo, bf16* __restrict__ Ko, bf16* __restrict__ Vo)
{
    __shared__ __attribute__((aligned(16))) char smem[131072];
    bf16 (*xs)[264] = (bf16(*)[264])smem;
    bf16* bufA = (bf16*)smem;
    bf16* bufB = (bf16*)(smem + 65536);

    int bid = blockIdx.x;
    int b = bid & 7, nt = bid >> 3;
    int n0 = nt * 128;
    int t = threadIdx.x;
    int lane = t & 63, w = t >> 6;
    int l32 = lane & 31, h = lane >> 5;
    int tokg = w >> 1;
    int og   = w & 1;

    int wofs[8];
#pragma unroll
    for (int jj = 0; jj < 8; ++jj) {
        int q = w * 8 + jj;
        int r2 = 2 * q + h;
        int cs = l32 ^ (r2 & 31);
        wofs[jj] = r2 * 512 + cs * 16;
    }

    {
        const float* xb = x + (size_t)b * DIN * NTOK;
#pragma unroll
        for (int it = 0; it < 16; ++it) {
            int flat = it * 512 + t;
            int c = flat >> 5;
            int nf = flat & 31;
            float4 v = *(const float4*)(xb + (size_t)c * NTOK + n0 + nf * 4);
            int nn = nf * 4;
            xs[nn + 0][c] = (bf16)v.x;
            xs[nn + 1][c] = (bf16)v.y;
            xs[nn + 2][c] = (bf16)v.z;
            xs[nn + 3][c] = (bf16)v.w;
        }
    }
    __syncthreads();

    bf16x8 xf[16];
#pragma unroll
    for (int ks = 0; ks < 16; ++ks)
        xf[ks] = *(const bf16x8*)&xs[tokg * 32 + l32][ks * 16 + h * 8];

    __syncthreads();

    {
        const char* src = (const char*)Wb;
#pragma unroll
        for (int jj = 0; jj < 8; ++jj)
            async16(src + wofs[jj], (char*)bufA + (w * 8 + jj) * 1024);
    }
    __syncthreads();

    for (int p = 0; p < 6; ++p) {
        if (p < 5) {
            bf16* nb = ((p + 1) & 1) ? bufB : bufA;
            const char* src = (const char*)Wb + (size_t)(p + 1) * 65536;
#pragma unroll
            for (int jj = 0; jj < 8; ++jj)
                async16(src + wofs[jj], (char*)nb + (w * 8 + jj) * 1024);
        }

        const bf16* wb = (p & 1) ? bufB : bufA;
        int mat = p >> 1, dhalf = p & 1;

        floatx16 acc[2];
#pragma unroll
        for (int dc = 0; dc < 2; ++dc)
#pragma unroll
            for (int i = 0; i < 16; ++i) acc[dc][i] = 0.0f;

        if (mat < 2) {
#pragma unroll
            for (int ks = 0; ks < 16; ++ks) {
#pragma unroll
                for (int dc = 0; dc < 2; ++dc) {
                    int row = og * 64 + dc * 32 + l32;
                    bf16x8 wf = *(const bf16x8*)((const char*)wb + row * 512 +
                                                 (((2 * ks + h) ^ (row & 31)) * 16));
                    acc[dc] = mfma32(xf[ks], wf, acc[dc]);
                }
            }
            bf16* Out = (mat == 0 ? Qo : Ko) + (size_t)b * NTOK * DIN;
#pragma unroll
            for (int dc = 0; dc < 2; ++dc) {
                int d = dhalf * 128 + og * 64 + dc * 32 + l32;
#pragma unroll
                for (int r = 0; r < 16; ++r) {
                    int tok = n0 + tokg * 32 + (r & 3) + 8 * (r >> 2) + 4 * h;
                    Out[(size_t)tok * DIN + d] = (bf16)acc[dc][r];
                }
            }
        } else {
#pragma unroll
            for (int ks = 0; ks < 16; ++ks) {
#pragma unroll
                for (int dc = 0; dc < 2; ++dc) {
                    int row = og * 64 + dc * 32 + l32;
                    bf16x8 wf = *(const bf16x8*)((const char*)wb + row * 512 +
                                                 (((2 * ks + h) ^ (row & 31)) * 16));
                    acc[dc] = mfma32(wf, xf[ks], acc[dc]);
                }
            }
            bf16* Out = Vo + (size_t)b * DIN * NTOK;
            int tok = n0 + tokg * 32 + l32;
#pragma unroll
            for (int dc = 0; dc < 2; ++dc)
#pragma unroll
                for (int r = 0; r < 16; ++r) {
                    int d = dhalf * 128 + og * 64 + dc * 32 + (r & 3) + 8 * (r >> 2) + 4 * h;
                    Out[(size_t)d * NTOK + tok] = (bf16)acc[dc][r];
                }
        }
        __syncthreads();
    }
}

// ---------------- kernel 3: attention (best verified: R2/R4 structure, no setprio) ----------------
// 7 experiments (traffic R3, vmcnt R5, occupancy R1/R6, homogeneous R7, setprio R8)
// all null/negative: this producer/consumer 8-wave structure at 153.5us = 895 TF is
// the documented plain-HIP attention plateau (m214 ~900 TF). Path beyond = fully
// co-designed HK 4-cluster rewrite (T16), not reachable by single-variable steps.
// Q,K: [B][N][256] bf16 ; V: [B][256][N] bf16 (=V^T) ; out: [B][256][N] fp32
// 512 thr = 8 waves. w<4: S-producers compute S^T = K.Q^T, exp, pack into Ps dbuf.
// w>=4: PV-consumers O^T[64d][128tok] from Ps + Vs. ONE barrier per iteration.
// All tiles conflict-free swizzle: 16B chunk c of row r at pos c^(r&7)^((r>>3)&3).
__global__ __launch_bounds__(512, 2) void attn_kernel(
    const bf16* __restrict__ Q, const bf16* __restrict__ K,
    const bf16* __restrict__ V, float* __restrict__ out)
{
    __shared__ bf16 Ks[2][64][256];   // 64 KB
    __shared__ bf16 Vs[2][256][64];   // 64 KB
    __shared__ bf16 Ps[2][128][64];   // 32 KB  (total 160 KB exactly)

    int bid = blockIdx.x;
    int b = bid & 7, qt = bid >> 3;   // batch -> XCD L2 locality
    int n0 = qt * 128;
    int t = threadIdx.x, lane = t & 63, w = t >> 6;
    int l32 = lane & 31, h = lane >> 5;
    int lkey = (l32 & 7) ^ ((l32 >> 3) & 3);   // swizzle key at every use site

    const bf16* Qb = Q + (size_t)b * NTOK * DIN;
    const bf16* Kb = K + (size_t)b * NTOK * DIN;
    const bf16* Vb = V + (size_t)b * DIN * NTOK;
    float* Lp = (float*)&Ps[0][0][0];   // reused AFTER last tile barrier (Ps dead)

    if (w < 4) {
        // ================= S-producer: S^T = K.Q^T =================
        int tokg = w >> 1, mg = w & 1;
        int krow = mg * 32 + l32;

        int koff[8];
#pragma unroll
        for (int jj = 0; jj < 8; ++jj) {
            int q = w * 8 + jj;
            int r = q * 2 + (lane >> 5);
            int ck = (lane & 31) ^ ((r & 7) ^ ((r >> 3) & 3));
            koff[jj] = (r * 256 + ck * 8) * 2;
        }

        bf16x8 qf[2][16];
#pragma unroll
        for (int ca = 0; ca < 2; ++ca) {
            const bf16* qrow = Qb + (size_t)(n0 + tokg * 64 + ca * 32 + l32) * DIN + h * 8;
#pragma unroll
            for (int ks = 0; ks < 16; ++ks) qf[ca][ks] = *(const bf16x8*)(qrow + ks * 16);
        }

        float lsum[2] = {0.0f, 0.0f};

        // prologue: K(0)->buf0, K(1)->buf1
#pragma unroll
        for (int jj = 0; jj < 8; ++jj) {
            async16((const char*)Kb + koff[jj], (bf16*)Ks[0] + (w * 8 + jj) * 512);
            async16((const char*)Kb + 32768 + koff[jj], (bf16*)Ks[1] + (w * 8 + jj) * 512);
        }
        __syncthreads();   // (1)

        // S^T(0) -> Ps[0]
        {
            const bf16* Krd = (const bf16*)Ks[0] + krow * 256;
            floatx16 st[2];
#pragma unroll
            for (int i = 0; i < 16; ++i) { st[0][i] = 0.0f; st[1][i] = 0.0f; }
#pragma unroll
            for (int ks = 0; ks < 16; ++ks) {
                bf16x8 kf = *(const bf16x8*)(Krd + (((2 * ks + h) ^ lkey) * 8));
                st[0] = mfma32(kf, qf[0][ks], st[0]);
                st[1] = mfma32(kf, qf[1][ks], st[1]);
            }
#pragma unroll
            for (int ca = 0; ca < 2; ++ca) {
                bf16* Prow = (bf16*)Ps[0] + (tokg * 64 + ca * 32 + l32) * 64;
                float tsum = 0.0f;
#pragma unroll
                for (int g = 0; g < 4; ++g) {
                    bf16x4 pk;
#pragma unroll
                    for (int i = 0; i < 4; ++i) {
                        float e = __expf(st[ca][g * 4 + i] * 0.0625f);
                        tsum += e;
                        pk[i] = (bf16)e;
                    }
                    *(bf16x4*)((char*)Prow + (((mg * 4 + g) ^ lkey) * 16) + h * 8) = pk;
                }
                lsum[ca] += tsum;
            }
        }
        __syncthreads();   // (2)

        for (int mt = 0; mt < 64; ++mt) {
            if (mt < 62) {   // DMA K(mt+2) -> Ks[mt&1]
                int kadd = (mt + 2) * 32768;
#pragma unroll
                for (int jj = 0; jj < 8; ++jj)
                    async16((const char*)Kb + kadd + koff[jj],
                            (bf16*)Ks[mt & 1] + (w * 8 + jj) * 512);
            }
            if (mt < 63) {
                const bf16* Krd = (const bf16*)Ks[(mt + 1) & 1] + krow * 256;
                floatx16 st[2];
#pragma unroll
                for (int i = 0; i < 16; ++i) { st[0][i] = 0.0f; st[1][i] = 0.0f; }
#pragma unroll
                for (int ks = 0; ks < 16; ++ks) {
                    bf16x8 kf = *(const bf16x8*)(Krd + (((2 * ks + h) ^ lkey) * 8));
                    st[0] = mfma32(kf, qf[0][ks], st[0]);
                    st[1] = mfma32(kf, qf[1][ks], st[1]);
                }
                bf16* Pw = (bf16*)Ps[(mt + 1) & 1];
#pragma unroll
                for (int ca = 0; ca < 2; ++ca) {
                    bf16* Prow = Pw + (tokg * 64 + ca * 32 + l32) * 64;
                    float tsum = 0.0f;
#pragma unroll
                    for (int g = 0; g < 4; ++g) {
                        bf16x4 pk;
#pragma unroll
                        for (int i = 0; i < 4; ++i) {
                            float e = __expf(st[ca][g * 4 + i] * 0.0625f);
                            tsum += e;
                            pk[i] = (bf16)e;
                        }
                        *(bf16x4*)((char*)Prow + (((mg * 4 + g) ^ lkey) * 16) + h * 8) = pk;
                    }
                    lsum[ca] += tsum;
                }
            }
            __syncthreads();   // single barrier per iter
        }

        // epilogue: h-pair reduce, publish row sums (Ps now dead -> Lp alias ok)
#pragma unroll
        for (int ca = 0; ca < 2; ++ca) {
            float sv = lsum[ca];
            sv += __shfl_xor(sv, 32);
            if (h == 0) Lp[mg * 128 + tokg * 64 + ca * 32 + l32] = sv;
        }
        __syncthreads();   // (3)
    } else {
        // ================= PV-consumer: O^T = V^T.P^T =================
        int slab = w - 4;

        int vofs[8];
#pragma unroll
        for (int jj = 0; jj < 8; ++jj) {
            int q = slab * 8 + jj;
            int d = q * 8 + (lane >> 3);
            int cv = (lane & 7) ^ ((d & 7) ^ ((d >> 3) & 3));
            vofs[jj] = (d * 4096 + cv * 8) * 2;
        }

        floatx16 oacc[8];   // [dc][tc]
#pragma unroll
        for (int i = 0; i < 8; ++i)
            for (int j = 0; j < 16; ++j) oacc[i][j] = 0.0f;

        // prologue: V(0)->buf0
#pragma unroll
        for (int jj = 0; jj < 8; ++jj)
            async16((const char*)Vb + vofs[jj], (bf16*)Vs[0] + (slab * 8 + jj) * 512);
        __syncthreads();   // (1)
        __syncthreads();   // (2)

        for (int mt = 0; mt < 64; ++mt) {
            if (mt < 63) {   // DMA V(mt+1) -> Vs[(mt+1)&1]
                int vadd = (mt + 1) * 128;
#pragma unroll
                for (int jj = 0; jj < 8; ++jj)
                    async16((const char*)Vb + vadd + vofs[jj],
                            (bf16*)Vs[(mt + 1) & 1] + (slab * 8 + jj) * 512);
            }
            const bf16* Vrd = (const bf16*)Vs[mt & 1];
            const char* Prd = (const char*)Ps[mt & 1];
#pragma unroll
            for (int kst = 0; kst < 4; ++kst) {
                bf16x8 va[2], pb[4];
#pragma unroll
                for (int dc = 0; dc < 2; ++dc) {
                    int d = slab * 64 + dc * 32 + l32;
                    va[dc] = *(const bf16x8*)(Vrd + d * 64 + (((kst * 2 + h) ^ lkey) * 8));
                }
#pragma unroll
                for (int tc = 0; tc < 4; ++tc)
                    pb[tc] = *(const bf16x8*)(Prd + (tc * 32 + l32) * 128 +
                                              (((kst * 2 + h) ^ lkey) * 16));
#pragma unroll
                for (int dc = 0; dc < 2; ++dc)
#pragma unroll
                    for (int tc = 0; tc < 4; ++tc)
                        oacc[dc * 4 + tc] = mfma32(va[dc], pb[tc], oacc[dc * 4 + tc]);
            }
            __syncthreads();   // single barrier per iter
        }

        __syncthreads();   // (3): Lp ready
        float* ob = out + (size_t)b * DIN * NTOK;
#pragma unroll
        for (int tc = 0; tc < 4; ++tc) {
            int tok = tc * 32 + l32;
            float rinv = 1.0f / (Lp[tok] + Lp[128 + tok]);
#pragma unroll
            for (int dc = 0; dc < 2; ++dc)
#pragma unroll
                for (int r = 0; r < 16; ++r) {
                    int d = slab * 64 + dc * 32 + (r & 3) + 8 * (r >> 2) + 4 * h;
                    ob[(size_t)d * NTOK + n0 + tok] = oacc[dc * 4 + tc][r] * rinv;
                }
        }
    }
}

// ---------------- launcher ----------------
extern "C" void kernel_launch(void* const* d_in, const int* in_sizes, int n_in,
                              void* d_out, int out_size, void* d_ws, size_t ws_size,
                              hipStream_t stream) {
    const float* x  = (const float*)d_in[0];
    const float* wq = (const float*)d_in[1];
    const float* wk = (const float*)d_in[2];
    const float* wv = (const float*)d_in[3];
    float* outf = (float*)d_out;

    char* ws = (char*)d_ws;
    bf16* Wb = (bf16*)(ws);                                  // 384 KB
    bf16* Qp = (bf16*)(ws + (1u << 20));                     // 16 MB
    bf16* Kp = (bf16*)(ws + (1u << 20) + (16u << 20));       // 16 MB
    bf16* Vp = (bf16*)(ws + (1u << 20) + (32u << 20));       // 16 MB

    convert_w<<<192, 256, 0, stream>>>(wq, wk, wv, Wb);
    proj_kernel<<<256, 512, 0, stream>>>(x, Wb, Qp, Kp, Vp);
    attn_kernel<<<256, 512, 0, stream>>>(Qp, Kp, Vp, outf);
}